// Round 1
// baseline (4335.713 us; speedup 1.0000x reference)
//
#include <hip/hip_runtime.h>
#include <hip/hip_bf16.h>
#include <math.h>

#define HIDDEN 2560
#define NH 32
#define NKV 8
#define HD 80
#define BATCH 2
#define SEQ 2048
#define QH_COLS (NH*HD)    // 2560
#define KV_COLS (NKV*HD)   // 640
#define ROWS (BATCH*SEQ)   // 4096

// ---------------- fp32 tiled GEMM: C[M,N] = A[M,K] @ B[K,N] ----------------
// 64x64 tile, BK=16, 256 threads, 4x4 micro-tile per thread.
#define BM 64
#define BN 64
#define BK 16

__global__ __launch_bounds__(256) void sgemm(const float* __restrict__ A,
                                             const float* __restrict__ B,
                                             float* __restrict__ C,
                                             int M, int N, int K) {
    __shared__ float As[BK][BM + 4];   // stored transposed: As[k][m]
    __shared__ float Bs[BK][BN + 4];
    const int tid = threadIdx.x;
    const int bm = blockIdx.y * BM;
    const int bn = blockIdx.x * BN;
    const int tx = tid & 15;
    const int ty = tid >> 4;
    float acc[4][4];
#pragma unroll
    for (int i = 0; i < 4; i++)
#pragma unroll
        for (int j = 0; j < 4; j++) acc[i][j] = 0.0f;

    for (int k0 = 0; k0 < K; k0 += BK) {
        // A tile: 64 rows x 16 k. thread loads 4 elems. c = tid&15 (k), r = tid>>4 (+16i)
#pragma unroll
        for (int i = 0; i < 4; i++) {
            int r = (tid >> 4) + i * 16;
            int c = tid & 15;
            As[c][r] = A[(size_t)(bm + r) * K + (k0 + c)];
        }
        // B tile: 16 k x 64 n. r = tid>>6 (+4i), c = tid&63
#pragma unroll
        for (int i = 0; i < 4; i++) {
            int r = (tid >> 6) + i * 4;
            int c = tid & 63;
            Bs[r][c] = B[(size_t)(k0 + r) * N + (bn + c)];
        }
        __syncthreads();
#pragma unroll
        for (int kk = 0; kk < BK; kk++) {
            float a[4], b[4];
#pragma unroll
            for (int i = 0; i < 4; i++) a[i] = As[kk][ty * 4 + i];
#pragma unroll
            for (int j = 0; j < 4; j++) b[j] = Bs[kk][tx * 4 + j];
#pragma unroll
            for (int i = 0; i < 4; i++)
#pragma unroll
                for (int j = 0; j < 4; j++) acc[i][j] += a[i] * b[j];
        }
        __syncthreads();
    }
#pragma unroll
    for (int i = 0; i < 4; i++)
#pragma unroll
        for (int j = 0; j < 4; j++)
            C[(size_t)(bm + ty * 4 + i) * N + (bn + tx * 4 + j)] = acc[i][j];
}

// ---------------- RoPE (in place on q and k buffers) ----------------
// idx -> (g in [0,4096), hh in [0,40), d in [0,40)); hh<32 -> Q head, else K head hh-32
__global__ __launch_bounds__(256) void rope_kernel(float* __restrict__ qb,
                                                   float* __restrict__ kb,
                                                   const float* __restrict__ cf,
                                                   const float* __restrict__ sf) {
    int idx = blockIdx.x * 256 + threadIdx.x;   // exactly 4096*40*40 threads
    int d  = idx % 40;
    int t  = idx / 40;
    int hh = t % (NH + NKV);
    int g  = t / (NH + NKV);
    int s  = g & (SEQ - 1);
    float c1 = cf[s * HD + d],      s1 = sf[s * HD + d];
    float c2 = cf[s * HD + d + 40], s2 = sf[s * HD + d + 40];
    float* p = (hh < NH) ? (qb + (size_t)g * QH_COLS + hh * HD)
                         : (kb + (size_t)g * KV_COLS + (hh - NH) * HD);
    float x1 = p[d];
    float x2 = p[d + 40];
    p[d]      = x1 * c1 - x2 * s1;
    p[d + 40] = x2 * c2 + x1 * s2;
}

// ---------------- flash-style causal attention ----------------
// grid: (SEQ/32, NH, BATCH), block 256. Q tile = 32 rows, K tile = 32.
// q layout: (b*S, NH*HD); k/v layout: (b*S, NKV*HD); o layout: (b*S, NH*HD)
#define QT 32
#define KT 32
#define QS_STRIDE 81   // pad 80->81: makes 8-row / strided-col LDS reads conflict-free
#define PS_STRIDE 33

__global__ __launch_bounds__(256) void attn_kernel(const float* __restrict__ qb,
                                                   const float* __restrict__ kb,
                                                   const float* __restrict__ vb,
                                                   float* __restrict__ ob) {
    __shared__ float Qs[QT][QS_STRIDE];
    __shared__ float Ks[KT][QS_STRIDE];
    __shared__ float Vs[KT][QS_STRIDE];
    __shared__ float Ps[QT][PS_STRIDE];
    __shared__ float m_l[QT], l_l[QT], al_l[QT];

    const int tid = threadIdx.x;
    const int qt  = blockIdx.x;
    const int h   = blockIdx.y;
    const int b   = blockIdx.z;
    const int kvh = h >> 2;              // 32 heads -> 8 kv heads (repeat factor 4)
    const float scale = 0.11180339887498949f;   // 1/sqrt(80)

    // load Q tile, pre-scaled
#pragma unroll
    for (int i = 0; i < 10; i++) {
        int e = tid + i * 256;           // < 2560
        int r = e / HD, c = e % HD;
        Qs[r][c] = qb[(size_t)(b * SEQ + qt * QT + r) * QH_COLS + h * HD + c] * scale;
    }
    if (tid < QT) { m_l[tid] = -3.0e38f; l_l[tid] = 0.0f; }

    float acc[10];
#pragma unroll
    for (int i = 0; i < 10; i++) acc[i] = 0.0f;
    const int r7 = tid >> 3;            // PV row: tid/8
    const int c0 = (tid & 7) * 10;      // PV col start

    // score phase mapping: 2x2 patch per thread
    const int rp = tid >> 4;            // 0..15 -> rows 2rp, 2rp+1
    const int cp = tid & 15;            // 0..15 -> cols 2cp, 2cp+1

    for (int kt = 0; kt <= qt; kt++) {
        __syncthreads();   // protect Ks/Vs from previous iteration's readers
#pragma unroll
        for (int i = 0; i < 10; i++) {
            int e = tid + i * 256;
            int r = e / HD, c = e % HD;
            size_t base = (size_t)(b * SEQ + kt * KT + r) * KV_COLS + kvh * HD + c;
            Ks[r][c] = kb[base];
            Vs[r][c] = vb[base];
        }
        __syncthreads();
        // scores: 2x2 per thread
        {
            float s00 = 0.f, s01 = 0.f, s10 = 0.f, s11 = 0.f;
            const int r0 = rp * 2, cgs = cp * 2;
            for (int d = 0; d < HD; d++) {
                float q0 = Qs[r0][d], q1 = Qs[r0 + 1][d];
                float k0 = Ks[cgs][d], k1 = Ks[cgs + 1][d];
                s00 += q0 * k0; s01 += q0 * k1;
                s10 += q1 * k0; s11 += q1 * k1;
            }
            int gq0 = qt * QT + r0;
            int gk0 = kt * KT + cgs;
            Ps[r0][cgs]         = (gk0     > gq0    ) ? -1.0e9f : s00;
            Ps[r0][cgs + 1]     = (gk0 + 1 > gq0    ) ? -1.0e9f : s01;
            Ps[r0 + 1][cgs]     = (gk0     > gq0 + 1) ? -1.0e9f : s10;
            Ps[r0 + 1][cgs + 1] = (gk0 + 1 > gq0 + 1) ? -1.0e9f : s11;
        }
        __syncthreads();
        // online softmax row update (threads 0..31, one per row)
        if (tid < QT) {
            int r = tid;
            float mo = m_l[r];
            float mx = mo;
            for (int j = 0; j < KT; j++) mx = fmaxf(mx, Ps[r][j]);
            float sum = 0.f;
            for (int j = 0; j < KT; j++) {
                float p = __expf(Ps[r][j] - mx);
                Ps[r][j] = p;
                sum += p;
            }
            float al = __expf(mo - mx);
            m_l[r] = mx;
            l_l[r] = l_l[r] * al + sum;
            al_l[r] = al;
        }
        __syncthreads();
        // PV accumulate: thread owns (row r7, cols c0..c0+9)
        {
            float al = al_l[r7];
#pragma unroll
            for (int i = 0; i < 10; i++) acc[i] *= al;
            for (int j = 0; j < KT; j++) {
                float p = Ps[r7][j];
#pragma unroll
                for (int i = 0; i < 10; i++) acc[i] += p * Vs[j][c0 + i];
            }
        }
    }
    __syncthreads();
    float inv = 1.0f / l_l[r7];
#pragma unroll
    for (int i = 0; i < 10; i++)
        ob[(size_t)(b * SEQ + qt * QT + r7) * QH_COLS + h * HD + c0 + i] = acc[i] * inv;
}

// ---------------- launch ----------------
extern "C" void kernel_launch(void* const* d_in, const int* in_sizes, int n_in,
                              void* d_out, int out_size, void* d_ws, size_t ws_size,
                              hipStream_t stream) {
    const float* x    = (const float*)d_in[0];
    const float* cf   = (const float*)d_in[1];
    const float* sf   = (const float*)d_in[2];
    const float* Wq   = (const float*)d_in[3];
    const float* Wk   = (const float*)d_in[4];
    const float* Wv   = (const float*)d_in[5];
    const float* Wo   = (const float*)d_in[6];
    float* out = (float*)d_out;

    float* qb = (float*)d_ws;                         // 4096 x 2560
    float* kb = qb + (size_t)ROWS * QH_COLS;          // 4096 x 640
    float* vb = kb + (size_t)ROWS * KV_COLS;          // 4096 x 640
    float* ob = vb + (size_t)ROWS * KV_COLS;          // 4096 x 2560

    dim3 blk(256);
    // QKV projections
    sgemm<<<dim3(QH_COLS / BN, ROWS / BM), blk, 0, stream>>>(x, Wq, qb, ROWS, QH_COLS, HIDDEN);
    sgemm<<<dim3(KV_COLS / BN, ROWS / BM), blk, 0, stream>>>(x, Wk, kb, ROWS, KV_COLS, HIDDEN);
    sgemm<<<dim3(KV_COLS / BN, ROWS / BM), blk, 0, stream>>>(x, Wv, vb, ROWS, KV_COLS, HIDDEN);
    // RoPE on q and k
    rope_kernel<<<(ROWS * (NH + NKV) * 40) / 256, blk, 0, stream>>>(qb, kb, cf, sf);
    // attention
    attn_kernel<<<dim3(SEQ / QT, NH, BATCH), blk, 0, stream>>>(qb, kb, vb, ob);
    // output projection
    sgemm<<<dim3(HIDDEN / BN, ROWS / BM), blk, 0, stream>>>(ob, Wo, out, ROWS, HIDDEN, HIDDEN);
}